// Round 1
// 803.223 us; speedup vs baseline: 1.8143x; 1.8143x over previous
//
#include <hip/hip_runtime.h>
#include <hip/hip_bf16.h>

typedef __attribute__((ext_vector_type(8))) short short8;   // 8 bf16 = 4 VGPRs
typedef __attribute__((ext_vector_type(4))) float float4v;  // MFMA accumulator

#define HH 28
#define WD 28
#define CIN 64
#define COUT 128
#define KTOT 288          // K = (j*3+k)*32 + l  (l-contiguous so MFMA frags are short8)

// Wbf[i][(j*3+k)*32 + l] = bf16(W[l][j][k][i]),  W flat: ((l*3+j)*3+k)*128 + i
__global__ __launch_bounds__(256) void prep_w_kernel(const float* __restrict__ W,
                                                     __hip_bfloat16* __restrict__ Wbf) {
    int idx = blockIdx.x * 256 + threadIdx.x;
    if (idx >= COUT * KTOT) return;
    int i = idx / KTOT;
    int K = idx - i * KTOT;
    int jk = K >> 5;
    int l = K & 31;
    int j = jk / 3;
    int k = jk - j * 3;
    Wbf[idx] = __float2bfloat16(W[((l * 3 + j) * 3 + k) * COUT + i]);
}

// One block per image m. 256 threads = 4 waves.
// LDS: V[rp 30][a 30][l 32] bf16 (rp = r+1, zero rows rp=0,29), byte-XOR-swizzled.
//      V0[rp 30][k 3][l 32] bf16 linear (special w=0 column; row rp=0 doubles as zero source).
__global__ __launch_bounds__(256) void conv_kernel(const float* __restrict__ x,
                                                   const __hip_bfloat16* __restrict__ Wbf,
                                                   float* __restrict__ out) {
    __shared__ __align__(16) char Vb[30 * 30 * 64];   // 57600 B
    __shared__ __align__(16) char V0b[30 * 3 * 64];   // 5760 B

    const int m = blockIdx.x;
    const int tid = threadIdx.x;
    const float* xm = x + (size_t)m * (CIN * HH * WD);

    // ---- phase 1a: build V. thread -> (rp, lq, a); one short8 (8 l) per iter.
    // V[l][r][a] = [a<28]*x[l][r][(a-1)%28] + [1<=a<=28]*x[l+32][r][(a-2)%28]
    for (int idx = tid; idx < 30 * 4 * 32; idx += 256) {
        int a  = idx & 31;
        int lq = (idx >> 5) & 3;
        int rp = idx >> 7;
        if (a >= 30) continue;
        int r = rp - 1;
        bool rok = (r >= 0) && (r < HH);
        bool m1 = rok && (a < 28);
        bool m2 = rok && (a >= 1) && (a <= 28);
        int i1 = a - 1; if (i1 < 0) i1 += 28;   // (a-1) mod 28
        int i2 = a - 2; if (i2 < 0) i2 += 28;   // (a-2) mod 28
        const float* x1 = xm + ((lq * 8) * HH + r) * WD;
        const float* x2 = x1 + 32 * HH * WD;
        short8 sv;
#pragma unroll
        for (int c = 0; c < 8; ++c) {
            float t = 0.f;
            if (m1) t += x1[c * HH * WD + i1];
            if (m2) t += x2[c * HH * WD + i2];
            __hip_bfloat16 hb = __float2bfloat16(t);
            sv[c] = *reinterpret_cast<short*>(&hb);
        }
        unsigned byte = (unsigned)(rp * 30 + a) * 64 + (unsigned)lq * 16;
        byte ^= (byte >> 3) & 0x30;             // bank swizzle (write == read formula)
        *(short8*)(Vb + byte) = sv;
    }

    // ---- phase 1b: special w=0 column. B[0][k]: k=0: x2[25]; k=1: x1[27]+x2[26]; k=2: x1[0]
    for (int idx = tid; idx < 30 * 3 * 32; idx += 256) {
        int l = idx & 31;
        int t3 = idx >> 5;       // rp*3 + k
        int k = t3 % 3;
        int rp = t3 / 3;
        int r = rp - 1;
        float v = 0.f;
        if (r >= 0 && r < HH) {
            const float* x1 = xm + (l * HH + r) * WD;
            const float* x2 = x1 + 32 * HH * WD;
            if (k == 0) v = x2[25];
            else if (k == 1) v = x1[27] + x2[26];
            else v = x1[0];
        }
        __hip_bfloat16 hb = __float2bfloat16(v);
        *(__hip_bfloat16*)(V0b + idx * 2) = hb;
    }
    __syncthreads();

    // ---- phase 2: hoist A into registers, then h-loop with no further barriers
    const int lane = tid & 63;
    const int wv = tid >> 6;          // wave -> i-base = wv*32
    const int row = lane & 15;
    const int q = lane >> 4;
    const unsigned qb = (unsigned)q * 16;

    short8 Areg[2][9];
#pragma unroll
    for (int mt = 0; mt < 2; ++mt) {
        const __hip_bfloat16* ap = Wbf + (wv * 32 + mt * 16 + row) * KTOT + q * 8;
#pragma unroll
        for (int s = 0; s < 9; ++s)
            Areg[mt][s] = *(const short8*)(ap + s * 32);
    }

    const bool spec0 = (row == 0);    // nt=0: w==0 -> V0 column
    const bool spec1 = (row >= 12);   // nt=1: w>=28 -> zero row (V0 rp=0 is all zeros)

    for (int h = 0; h < HH; ++h) {
        float4v acc[2][2] = {};
#pragma unroll
        for (int s = 0; s < 9; ++s) {
            const int j = s / 3;
            const int k = s - j * 3;
            const int rp = h + j;                 // r = h+j-1, padded
            // nt=0: w = row, a = w+k-1 in [0,17]
            int a0 = row + k - 1;
            unsigned b0 = (unsigned)((rp * 30 + a0) * 64) + qb;
            b0 ^= (b0 >> 3) & 0x30;
            const char* p0 = spec0 ? (V0b + (unsigned)(rp * 3 + k) * 64 + qb)
                                   : (Vb + b0);
            // nt=1: w = row+16, a = w+k-1 in [15,28] (only lanes w<28 use it)
            unsigned b1 = (unsigned)((rp * 30 + (row + 15 + k)) * 64) + qb;
            b1 ^= (b1 >> 3) & 0x30;
            const char* p1 = spec1 ? (V0b + qb) : (Vb + b1);

            short8 bfr0 = *(const short8*)p0;     // ds_read_b128, conflict-free
            short8 bfr1 = *(const short8*)p1;

            acc[0][0] = __builtin_amdgcn_mfma_f32_16x16x32_bf16(Areg[0][s], bfr0, acc[0][0], 0, 0, 0);
            acc[1][0] = __builtin_amdgcn_mfma_f32_16x16x32_bf16(Areg[1][s], bfr0, acc[1][0], 0, 0, 0);
            acc[0][1] = __builtin_amdgcn_mfma_f32_16x16x32_bf16(Areg[0][s], bfr1, acc[0][1], 0, 0, 0);
            acc[1][1] = __builtin_amdgcn_mfma_f32_16x16x32_bf16(Areg[1][s], bfr1, acc[1][1], 0, 0, 0);
        }
        // epilogue: C/D layout col=lane&15 (=w), row=q*4+rr (i offset)
#pragma unroll
        for (int mt = 0; mt < 2; ++mt) {
            const int ibase = wv * 32 + mt * 16 + q * 4;
            float* op0 = out + (((size_t)m * COUT + ibase) * HH + h) * WD;
#pragma unroll
            for (int rr = 0; rr < 4; ++rr) {
                op0[rr * (HH * WD) + row] = acc[mt][0][rr];
                if (row < 12) op0[rr * (HH * WD) + 16 + row] = acc[mt][1][rr];
            }
        }
    }
}

extern "C" void kernel_launch(void* const* d_in, const int* in_sizes, int n_in,
                              void* d_out, int out_size, void* d_ws, size_t ws_size,
                              hipStream_t stream) {
    const float* x = (const float*)d_in[0];   // (1024, 64, 28, 28) fp32
    const float* W = (const float*)d_in[1];   // (32, 3, 3, 128) fp32
    float* out = (float*)d_out;               // (1024, 128, 28, 28) fp32
    __hip_bfloat16* Wbf = (__hip_bfloat16*)d_ws;  // 128*288 bf16 = 73728 B

    prep_w_kernel<<<(COUT * KTOT + 255) / 256, 256, 0, stream>>>(W, Wbf);
    conv_kernel<<<1024, 256, 0, stream>>>(x, Wbf, out);
}

// Round 2
// 749.110 us; speedup vs baseline: 1.9454x; 1.0722x over previous
//
#include <hip/hip_runtime.h>
#include <hip/hip_bf16.h>

typedef __attribute__((ext_vector_type(8))) short short8;   // 8 bf16 = 4 VGPRs
typedef __attribute__((ext_vector_type(4))) float float4v;  // MFMA accumulator

#define HH 28
#define WD 28
#define CIN 64
#define COUT 128
#define KTOT 288          // K = (j*3+k)*32 + l  (l-contiguous so MFMA frags are short8)
#define HB 14             // output rows per block (h-split)
#define RP 16             // local padded V rows = HB+2
#define V0OFF (RP * 30 * 64)        // 30720
#define ZOFF  (V0OFF + RP * 3 * 64) // 33792  (64B zero slot for w>=28 lanes)
#define LDSZ  (ZOFF + 64)           // 33856 -> 4 blocks/CU

// Wbf[i][(j*3+k)*32 + l] = bf16(W[l][j][k][i]),  W flat: ((l*3+j)*3+k)*128 + i
__global__ __launch_bounds__(256) void prep_w_kernel(const float* __restrict__ W,
                                                     __hip_bfloat16* __restrict__ Wbf) {
    int idx = blockIdx.x * 256 + threadIdx.x;
    if (idx >= COUT * KTOT) return;
    int i = idx / KTOT;
    int K = idx - i * KTOT;
    int jk = K >> 5;
    int l = K & 31;
    int j = jk / 3;
    int k = jk - j * 3;
    Wbf[idx] = __float2bfloat16(W[((l * 3 + j) * 3 + k) * COUT + i]);
}

// One block per (h-half, image). 256 threads = 4 waves.
// LDS V[rp RP][a 30][l 32] bf16 XOR-swizzled; V0[rp RP][k 3][l 32] linear; 64B zero slot.
__global__ __launch_bounds__(256, 4) void conv_kernel(const float* __restrict__ x,
                                                      const __hip_bfloat16* __restrict__ Wbf,
                                                      float* __restrict__ out) {
    __shared__ __align__(16) char L[LDSZ];

    const int hb = blockIdx.x;          // 0..1 -> h in [hb*14, hb*14+14)
    const int m  = blockIdx.y;
    const int tid = threadIdx.x;
    const float* xm = x + (size_t)m * (CIN * HH * WD);

    const int lane = tid & 63;
    const int wv = tid >> 6;            // wave -> i-base = wv*32
    const int row = lane & 15;
    const int q = lane >> 4;
    const unsigned qb = (unsigned)q * 16;

    // ---- A fragments (global, L2-resident). Issued BEFORE the LDS phase so the
    // global latency overlaps phase-1 work.
    short8 Areg[2][9];
#pragma unroll
    for (int mt = 0; mt < 2; ++mt) {
        const __hip_bfloat16* ap = Wbf + (wv * 32 + mt * 16 + row) * KTOT + q * 8;
#pragma unroll
        for (int s = 0; s < 9; ++s)
            Areg[mt][s] = *(const short8*)(ap + s * 32);
    }

    if (tid < 16) *(float*)(L + ZOFF + tid * 4) = 0.f;   // zero slot

    // ---- phase 1a: V[l][r][a] = [a<28]*x[l][r][(a-1)%28] + [1<=a<=28]*x[l+32][r][(a-2)%28]
    for (int idx = tid; idx < RP * 4 * 32; idx += 256) {
        int a  = idx & 31;
        int lq = (idx >> 5) & 3;
        int rp = idx >> 7;
        if (a < 30) {
            int r = hb * HB + rp - 1;
            bool rok = (r >= 0) && (r < HH);
            bool m1 = rok && (a < 28);
            bool m2 = rok && (a >= 1) && (a <= 28);
            int i1 = a - 1; if (i1 < 0) i1 += 28;   // (a-1) mod 28
            int i2 = a - 2; if (i2 < 0) i2 += 28;   // (a-2) mod 28
            const float* x1 = xm + ((lq * 8) * HH + r) * WD;
            const float* x2 = x1 + 32 * HH * WD;
            short8 sv;
#pragma unroll
            for (int c = 0; c < 8; ++c) {
                float t = 0.f;
                if (m1) t += x1[c * HH * WD + i1];
                if (m2) t += x2[c * HH * WD + i2];
                __hip_bfloat16 hv = __float2bfloat16(t);
                sv[c] = *reinterpret_cast<short*>(&hv);
            }
            unsigned byte = (unsigned)(rp * 30 + a) * 64 + (unsigned)lq * 16;
            byte ^= (byte >> 3) & 0x30;             // bank swizzle (write == read formula)
            *(short8*)(L + byte) = sv;
        }
    }

    // ---- phase 1b: special w=0 column. k=0: x2[25]; k=1: x1[27]+x2[26]; k=2: x1[0]
    for (int idx = tid; idx < RP * 3 * 32; idx += 256) {
        int l = idx & 31;
        int t3 = idx >> 5;       // rp*3 + k
        int k = t3 % 3;
        int rp = t3 / 3;
        int r = hb * HB + rp - 1;
        float v = 0.f;
        if (r >= 0 && r < HH) {
            const float* x1 = xm + (l * HH + r) * WD;
            const float* x2 = x1 + 32 * HH * WD;
            if (k == 0) v = x2[25];
            else if (k == 1) v = x1[27] + x2[26];
            else v = x1[0];
        }
        __hip_bfloat16 hv = __float2bfloat16(v);
        *(__hip_bfloat16*)(L + V0OFF + idx * 2) = hv;
    }
    __syncthreads();

    // ---- phase 2: h-loop, no further barriers
    const bool spec0 = (row == 0);    // nt=0: w==0 -> V0 column
    const bool spec1 = (row >= 12);   // nt=1: w>=28 -> zero slot

    for (int hl = 0; hl < HB; ++hl) {
        float4v acc[2][2] = {};
#pragma unroll
        for (int s = 0; s < 9; ++s) {
            const int j = s / 3;
            const int k = s - j * 3;
            const int rp = hl + j;                 // local padded row
            // nt=0: w = row, a = w+k-1
            int a0 = row + k - 1;
            unsigned b0 = (unsigned)((rp * 30 + a0) * 64) + qb;
            b0 ^= (b0 >> 3) & 0x30;
            unsigned off0 = spec0 ? (unsigned)(V0OFF + (rp * 3 + k) * 64) + qb : b0;
            // nt=1: w = row+16, a = w+k-1 (only lanes w<28 use it)
            unsigned b1 = (unsigned)((rp * 30 + (row + 15 + k)) * 64) + qb;
            b1 ^= (b1 >> 3) & 0x30;
            unsigned off1 = spec1 ? (unsigned)ZOFF + qb : b1;

            short8 bfr0 = *(const short8*)(L + off0);   // ds_read_b128
            short8 bfr1 = *(const short8*)(L + off1);

            acc[0][0] = __builtin_amdgcn_mfma_f32_16x16x32_bf16(Areg[0][s], bfr0, acc[0][0], 0, 0, 0);
            acc[1][0] = __builtin_amdgcn_mfma_f32_16x16x32_bf16(Areg[1][s], bfr0, acc[1][0], 0, 0, 0);
            acc[0][1] = __builtin_amdgcn_mfma_f32_16x16x32_bf16(Areg[0][s], bfr1, acc[0][1], 0, 0, 0);
            acc[1][1] = __builtin_amdgcn_mfma_f32_16x16x32_bf16(Areg[1][s], bfr1, acc[1][1], 0, 0, 0);
        }
        // epilogue: C/D layout col=lane&15 (=w), row=q*4+rr (i offset)
        const int h = hb * HB + hl;
#pragma unroll
        for (int mt = 0; mt < 2; ++mt) {
            const int ibase = wv * 32 + mt * 16 + q * 4;
            float* op0 = out + (((size_t)m * COUT + ibase) * HH + h) * WD;
#pragma unroll
            for (int rr = 0; rr < 4; ++rr) {
                op0[rr * (HH * WD) + row] = acc[mt][0][rr];
                if (row < 12) op0[rr * (HH * WD) + 16 + row] = acc[mt][1][rr];
            }
        }
    }
}

extern "C" void kernel_launch(void* const* d_in, const int* in_sizes, int n_in,
                              void* d_out, int out_size, void* d_ws, size_t ws_size,
                              hipStream_t stream) {
    const float* x = (const float*)d_in[0];   // (1024, 64, 28, 28) fp32
    const float* W = (const float*)d_in[1];   // (32, 3, 3, 128) fp32
    float* out = (float*)d_out;               // (1024, 128, 28, 28) fp32
    __hip_bfloat16* Wbf = (__hip_bfloat16*)d_ws;  // 128*288 bf16 = 73728 B

    prep_w_kernel<<<(COUT * KTOT + 255) / 256, 256, 0, stream>>>(W, Wbf);
    conv_kernel<<<dim3(2, 1024), 256, 0, stream>>>(x, Wbf, out);
}